// Round 2
// baseline (7401.446 us; speedup 1.0000x reference)
//
#include <hip/hip_runtime.h>

#define B_    64
#define L1C   4093
#define L2C   4086
#define L3C   4071
#define TDEC  60

static __device__ __forceinline__ float sigf(float x){ return 1.f/(1.f + __expf(-x)); }
static __device__ __forceinline__ float dot4(float4 w, float4 x){
  return fmaf(w.x,x.x, fmaf(w.y,x.y, fmaf(w.z,x.z, w.w*x.w)));
}
static __device__ __forceinline__ unsigned f2bf(float f){
  unsigned u = __float_as_uint(f);
  u = u + 0x7fffu + ((u >> 16) & 1u);   // RNE to bf16
  return (u >> 16);
}

// ---------------- conv stack ----------------
// in: (B, Lin, CIN) row-major; w: (COUT, CIN, KW); out: (B, Lout, COUT); relu.
// conv3 packs output to bf16 pairs (uint) for the attention stream.
template<int CIN,int COUT,int KW,bool BF16OUT>
__global__ __launch_bounds__(256) void k_conv(
    const float* __restrict__ in, const float* __restrict__ w,
    const float* __restrict__ bias, void* __restrict__ outp,
    int Lin_, int Lout_)
{
  int g = blockIdx.x*256 + threadIdx.x;
  int bi = g / Lout_;
  int l  = g - bi*Lout_;
  if (bi >= B_) return;
  float acc[COUT];
#pragma unroll
  for (int o=0;o<COUT;o++) acc[o] = bias[o];
  const float* ip = in + ((size_t)bi*Lin_ + l)*CIN;
  for (int k=0;k<KW;k++){
#pragma unroll
    for (int i4=0;i4<CIN/4;i4++){
      float4 xv = *(const float4*)(ip + k*CIN + i4*4);
#pragma unroll
      for (int c=0;c<4;c++){
        float xs = (&xv.x)[c];
        int i = i4*4+c;
#pragma unroll
        for (int o=0;o<COUT;o++)
          acc[o] = fmaf(xs, w[(o*CIN + i)*KW + k], acc[o]);  // uniform idx -> s_load
      }
    }
  }
  if constexpr (BF16OUT){
    unsigned* op = (unsigned*)outp + ((size_t)bi*Lout_ + l)*(COUT/2);
#pragma unroll
    for (int o2=0;o2<COUT/2;o2++){
      unsigned lo = f2bf(fmaxf(acc[2*o2],0.f));
      unsigned hi = f2bf(fmaxf(acc[2*o2+1],0.f));
      op[o2] = lo | (hi<<16);
    }
  } else {
    float* op = (float*)outp + ((size_t)bi*Lout_ + l)*COUT;
#pragma unroll
    for (int o=0;o<COUT;o++) op[o] = fmaxf(acc[o],0.f);
  }
}

// ---------------- dec1: attention scan (per step) ----------------
// grid (chunk=8, b=64); enc bf16-packed [b][l][16 uints]; computes v=h@attn_w
// in-block for BOTH dirs, then per-chunk online-softmax partials:
// parts[d][b][chunk] = {m, sumexp, ctx_num[32]}
__global__ __launch_bounds__(256) void k_attn(
    const unsigned* __restrict__ enc, const float* __restrict__ attn_w,
    const float* __restrict__ h_state, float* __restrict__ parts)
{
  int chunk = blockIdx.x, b = blockIdx.y, tid = threadIdx.x;
  int lc0 = chunk*512;
  int len = min(512, L3C - lc0);
  __shared__ __align__(16) unsigned encT[512*16];   // 32KB bf16 pairs
  __shared__ float vl[2][32];
  __shared__ float e_l[2][512];
  __shared__ float red[256];
  __shared__ float scr[512];
  {
    const uint4* src = (const uint4*)(enc + ((size_t)b*L3C + lc0)*16);
    int n4 = len*4;
    for (int i = tid; i < 2048; i += 256){
      uint4 v = (i < n4) ? src[i] : make_uint4(0,0,0,0);
      ((uint4*)encT)[i] = v;
    }
  }
  { // v[d][c] = sum_u h[d][b][u] * attn_w[u][c]
    int c = tid & 31, d = (tid>>5)&1, part = tid>>6;
    const float* hp = h_state + (size_t)d*16384 + (size_t)b*256 + part*64;
    const float* wp = attn_w + (size_t)(part*64)*32 + c;
    float s = 0.f;
    for (int u=0;u<64;u++) s = fmaf(hp[u], wp[u*32], s);
    red[tid] = s;
  }
  __syncthreads();
  if (tid < 64){
    float v = red[tid] + red[tid+64] + red[tid+128] + red[tid+192];
    vl[tid>>5][tid&31] = v;
  }
  __syncthreads();
  for (int d=0; d<2; d++){
    float al[2];
#pragma unroll
    for (int r=0;r<2;r++){
      int l = r*256 + tid;
      const unsigned* ep = encT + l*16;
      float s = 0.f;
#pragma unroll
      for (int c2=0;c2<16;c2++){
        unsigned u = ep[c2];
        s = fmaf(__uint_as_float(u<<16),        vl[d][2*c2],   s);
        s = fmaf(__uint_as_float(u & 0xffff0000u), vl[d][2*c2+1], s);
      }
      al[r] = (l < len) ? s : -3.0e38f;
    }
    float m = fmaxf(al[0], al[1]);
#pragma unroll
    for (int off=32; off; off>>=1) m = fmaxf(m, __shfl_xor(m, off));
    if ((tid&63)==0) red[tid>>6] = m;
    __syncthreads();
    m = fmaxf(fmaxf(red[0],red[1]), fmaxf(red[2],red[3]));
    float ssum = 0.f;
#pragma unroll
    for (int r=0;r<2;r++){
      int l = r*256 + tid;
      float e = (l < len) ? __expf(al[r]-m) : 0.f;
      e_l[d][l] = e;
      ssum += e;
    }
#pragma unroll
    for (int off=32; off; off>>=1) ssum += __shfl_xor(ssum, off);
    if ((tid&63)==0) red[4 + (tid>>6)] = ssum;
    __syncthreads();
    float S = red[4]+red[5]+red[6]+red[7];
    // ctx numerator partials
    int c2 = tid & 15, grp = tid >> 4;
    float a0=0.f, a1=0.f;
    for (int l=grp; l<512; l+=16){
      float e = e_l[d][l];
      unsigned u = encT[l*16 + c2];
      a0 = fmaf(e, __uint_as_float(u<<16),         a0);
      a1 = fmaf(e, __uint_as_float(u & 0xffff0000u), a1);
    }
    scr[(grp*16 + c2)*2 + 0] = a0;
    scr[(grp*16 + c2)*2 + 1] = a1;
    __syncthreads();
    float* pp = parts + (size_t)(((d*64 + b)*8) + chunk)*34;
    if (tid < 32){
      int cc2 = tid>>1, comp = tid&1;
      float s2 = 0.f;
#pragma unroll
      for (int gg=0; gg<16; gg++) s2 += scr[(gg*16+cc2)*2+comp];
      pp[2 + cc2*2 + comp] = s2;
    }
    if (tid==32) pp[0] = m;
    if (tid==33) pp[1] = S;
    __syncthreads();
  }
}

// ---------------- dec1: combine + LSTM cell (per step) ----------------
// grid (uc=32, d=2). Double-buffered h (h_in -> h_out) to avoid cross-block race.
__global__ __launch_bounds__(256) void k_lstm1(
    const float* __restrict__ parts,
    const float* __restrict__ wih, const float* __restrict__ whh,
    const float* __restrict__ bih, const float* __restrict__ bhh,
    const float* __restrict__ h_in, float* __restrict__ h_out,
    float* __restrict__ c_state, float* __restrict__ d2in, int t)
{
  int uc = blockIdx.x, d = blockIdx.y, tid = threadIdx.x;
  __shared__ __align__(16) float ctxs[64][36];
  if (tid < 64){
    int b = tid;
    const float* pp = parts + (size_t)((d*64 + b)*8)*34;
    float M = -3.0e38f;
#pragma unroll
    for (int ch=0;ch<8;ch++) M = fmaxf(M, pp[ch*34]);
    float S = 0.f; float wx[8];
#pragma unroll
    for (int ch=0;ch<8;ch++){ wx[ch] = __expf(pp[ch*34]-M); S = fmaf(pp[ch*34+1], wx[ch], S); }
    float inv = 1.f/S;
#pragma unroll
    for (int c=0;c<32;c++){
      float s = 0.f;
#pragma unroll
      for (int ch=0;ch<8;ch++) s = fmaf(pp[ch*34+2+c], wx[ch], s);
      ctxs[b][c] = s*inv;
    }
  }
  __syncthreads();
  int ul = tid & 7, bp = tid >> 3;
  int u = uc*8 + ul;
  int b0 = bp*2;
  float g[4][2];
#pragma unroll
  for (int q=0;q<4;q++){
    float bs = bih[d*1024 + q*256 + u] + bhh[d*1024 + q*256 + u];
    g[q][0] = bs; g[q][1] = bs;
  }
#pragma unroll
  for (int c4=0;c4<8;c4++){
    float4 x0 = *(const float4*)&ctxs[b0][c4*4];
    float4 x1 = *(const float4*)&ctxs[b0+1][c4*4];
#pragma unroll
    for (int q=0;q<4;q++){
      float4 w4 = *(const float4*)(wih + (size_t)(d*1024 + q*256 + u)*32 + c4*4);
      g[q][0] += dot4(w4,x0); g[q][1] += dot4(w4,x1);
    }
  }
  const float* hb0 = h_in + (size_t)d*16384 + (size_t)b0*256;
  for (int j4=0;j4<64;j4++){
    float4 h0 = *(const float4*)(hb0 + j4*4);
    float4 h1 = *(const float4*)(hb0 + 256 + j4*4);
#pragma unroll
    for (int q=0;q<4;q++){
      float4 w4 = *(const float4*)(whh + (size_t)(d*1024 + q*256 + u)*256 + j4*4);
      g[q][0] += dot4(w4,h0); g[q][1] += dot4(w4,h1);
    }
  }
#pragma unroll
  for (int b2=0;b2<2;b2++){
    int b = b0 + b2;
    float ii = sigf(g[0][b2]);
    float ff = sigf(g[1][b2]);
    float gg = tanhf(g[2][b2]);
    float oo = sigf(g[3][b2]);
    size_t idx = (size_t)d*16384 + (size_t)b*256 + u;
    float cn = fmaf(ff, c_state[idx], ii*gg);
    float hn = oo * tanhf(cn);
    c_state[idx] = cn;
    h_out[idx] = hn;
    int tout = d ? (59 - t) : t;
    d2in[((size_t)b*60 + tout)*512 + d*256 + u] = hn;
  }
}

// ---------------- generic fp32 GEMM: C = A(MxK) @ W(NxK)^T + b1 + b2 ----------------
// grid (M/128, N/128, z); W/C/bias offset by z*stride. 128x128 tile, 8x8/thread.
__global__ __launch_bounds__(256) void k_gemm(
    const float* __restrict__ A, const float* __restrict__ W,
    float* __restrict__ C, const float* __restrict__ b1, const float* __restrict__ b2,
    int K, int ldc, size_t sW, size_t sC, int sB)
{
  int m0 = blockIdx.x * 128, n0 = blockIdx.y * 128, z = blockIdx.z;
  const float* Wz = W + (size_t)z*sW;
  float* Cz = C + (size_t)z*sC;
  const float* b1z = b1 + (size_t)z*sB;
  const float* b2z = b2 ? (b2 + (size_t)z*sB) : nullptr;
  __shared__ __align__(16) float As[16][132];
  __shared__ __align__(16) float Bs[16][132];
  int tid = threadIdx.x;
  int tx = tid & 15, ty = tid >> 4;
  int r = tid >> 2, c4 = tid & 3;
  float acc[8][8] = {};
  for (int k0=0; k0<K; k0+=16){
#pragma unroll
    for (int h=0; h<2; h++){
      int rr = r + h*64;
      float4 av = *(const float4*)(A  + (size_t)(m0+rr)*K + k0 + c4*4);
      float4 bv = *(const float4*)(Wz + (size_t)(n0+rr)*K + k0 + c4*4);
      As[c4*4+0][rr]=av.x; As[c4*4+1][rr]=av.y; As[c4*4+2][rr]=av.z; As[c4*4+3][rr]=av.w;
      Bs[c4*4+0][rr]=bv.x; Bs[c4*4+1][rr]=bv.y; Bs[c4*4+2][rr]=bv.z; Bs[c4*4+3][rr]=bv.w;
    }
    __syncthreads();
#pragma unroll
    for (int kk=0; kk<16; kk++){
      float a[8], bb[8];
      *(float4*)&a[0]  = *(const float4*)&As[kk][ty*8];
      *(float4*)&a[4]  = *(const float4*)&As[kk][ty*8+4];
      *(float4*)&bb[0] = *(const float4*)&Bs[kk][tx*8];
      *(float4*)&bb[4] = *(const float4*)&Bs[kk][tx*8+4];
#pragma unroll
      for (int i=0;i<8;i++)
#pragma unroll
        for (int j=0;j<8;j++)
          acc[i][j] = fmaf(a[i], bb[j], acc[i][j]);
    }
    __syncthreads();
  }
  float bb1[8];
#pragma unroll
  for (int j=0;j<8;j++){
    int n = n0 + tx*8 + j;
    bb1[j] = b1z[n] + (b2z ? b2z[n] : 0.f);
  }
#pragma unroll
  for (int i=0;i<8;i++){
    int m = m0 + ty*8 + i;
    float o[8];
#pragma unroll
    for (int j=0;j<8;j++) o[j] = acc[i][j] + bb1[j];
    *(float4*)(Cz + (size_t)m*ldc + n0 + tx*8)     = *(const float4*)&o[0];
    *(float4*)(Cz + (size_t)m*ldc + n0 + tx*8 + 4) = *(const float4*)&o[4];
  }
}

// ---------------- dec2: persistent recurrent kernel ----------------
// grid (bp=32, d=2): block owns (dir, b-pair), loops all 60 steps; h in LDS.
__global__ __launch_bounds__(256) void k_rec(
    const float* __restrict__ xg,   // [2][64][60][1024] precomputed x@wih^T+biases
    const float* __restrict__ whh,  // [2][1024][256]
    float* __restrict__ out)        // [64][60][512]
{
  int bp = blockIdx.x, d = blockIdx.y, tid = threadIdx.x;
  int b0 = bp*2;
  __shared__ __align__(16) float hls[2][256];
  float c0 = 0.f, c1 = 0.f;
  hls[0][tid] = 0.f; hls[1][tid] = 0.f;
  __syncthreads();
  const float* wp = whh + (size_t)d*1024*256;
  for (int step=0; step<TDEC; step++){
    int t = d ? (TDEC-1-step) : step;
    float g[4][2];
#pragma unroll
    for (int q=0;q<4;q++){
      g[q][0] = xg[(((size_t)d*64 + b0  )*60 + t)*1024 + q*256 + tid];
      g[q][1] = xg[(((size_t)d*64 + b0+1)*60 + t)*1024 + q*256 + tid];
    }
    for (int j4=0;j4<64;j4++){
      float4 h0 = *(const float4*)&hls[0][j4*4];
      float4 h1 = *(const float4*)&hls[1][j4*4];
#pragma unroll
      for (int q=0;q<4;q++){
        float4 w4 = *(const float4*)(wp + ((size_t)q*256 + tid)*256 + j4*4);
        g[q][0] += dot4(w4,h0); g[q][1] += dot4(w4,h1);
      }
    }
    float hn[2];
#pragma unroll
    for (int b2=0;b2<2;b2++){
      float ii = sigf(g[0][b2]);
      float ff = sigf(g[1][b2]);
      float gg = tanhf(g[2][b2]);
      float oo = sigf(g[3][b2]);
      float& cc = b2 ? c1 : c0;
      cc = fmaf(ff, cc, ii*gg);
      hn[b2] = oo * tanhf(cc);
      out[(((size_t)(b0+b2))*60 + t)*512 + d*256 + tid] = hn[b2];
    }
    __syncthreads();
    hls[0][tid] = hn[0]; hls[1][tid] = hn[1];
    __syncthreads();
  }
}

extern "C" void kernel_launch(void* const* d_in, const int* in_sizes, int n_in,
                              void* d_out, int out_size, void* d_ws, size_t ws_size,
                              hipStream_t stream) {
  const float* x      = (const float*)d_in[0];
  const float* cw1    = (const float*)d_in[1];
  const float* cb1    = (const float*)d_in[2];
  const float* cw2    = (const float*)d_in[3];
  const float* cb2    = (const float*)d_in[4];
  const float* cw3    = (const float*)d_in[5];
  const float* cb3    = (const float*)d_in[6];
  const float* attn_w = (const float*)d_in[7];
  // d_in[8] attn_b: constant over softmax axis -> drops out analytically
  const float* d1_wih = (const float*)d_in[9];
  const float* d1_whh = (const float*)d_in[10];
  const float* d1_bih = (const float*)d_in[11];
  const float* d1_bhh = (const float*)d_in[12];
  const float* w2_ih0 = (const float*)d_in[13];
  const float* w2_hh0 = (const float*)d_in[14];
  const float* b2_ih0 = (const float*)d_in[15];
  const float* b2_hh0 = (const float*)d_in[16];
  const float* w2_ih1 = (const float*)d_in[17];
  const float* w2_hh1 = (const float*)d_in[18];
  const float* b2_ih1 = (const float*)d_in[19];
  const float* b2_hh1 = (const float*)d_in[20];
  const float* out_w  = (const float*)d_in[21];
  const float* out_b  = (const float*)d_in[22];

  char* ws = (char*)d_ws;
  size_t off = 0;
  // enc bf16-packed (B, L3C, 32ch) = 64*4071*64 B = 16,674,816 B; pad to 16,675,840.
  unsigned* enc = (unsigned*)(ws + off); off += 16675840;
  size_t off_h1 = off;
  float* h1buf = (float*)(ws + off); off += 8382464;               // (B,4093,8)
  float* h2buf = (float*)(ws + off); off += 16736256;              // (B,4086,16)
  float* d2in  = (float*)(ws + off_h1);                            // reuse: (B,60,512)
  float* l0    = (float*)(ws + off_h1 + 7864320);
  float* l1    = (float*)(ws + off_h1 + 15728640);
  float* xg    = (float*)(ws + off); off += 31457280;              // [2][B][60][1024]
  float* hA    = (float*)(ws + off); off += 131072;                // h dbuf A [2][B][256]
  float* hB    = (float*)(ws + off); off += 131072;                // h dbuf B
  float* cS    = (float*)(ws + off); off += 131072;                // c state
  float* parts = (float*)(ws + off); off += 2*64*8*34*4;           // attn partials
  (void)ws_size; (void)in_sizes; (void)n_in; (void)out_size;

  hipMemsetAsync(hA, 0, 3*131072, stream);   // zero hA, hB, cS (contiguous)

  int g1 = (B_*L1C + 255)/256;
  k_conv<64,8,4,false><<<g1,256,0,stream>>>(x, cw1, cb1, h1buf, 4096, L1C);
  int g2 = (B_*L2C + 255)/256;
  k_conv<8,16,8,false><<<g2,256,0,stream>>>(h1buf, cw2, cb2, h2buf, L1C, L2C);
  int g3 = (B_*L3C + 255)/256;
  k_conv<16,32,16,true><<<g3,256,0,stream>>>(h2buf, cw3, cb3, enc, L2C, L3C);

  float* hcur = hA; float* hnxt = hB;
  for (int t=0; t<TDEC; t++){
    k_attn<<<dim3(8,64),256,0,stream>>>(enc, attn_w, hcur, parts);
    k_lstm1<<<dim3(32,2),256,0,stream>>>(parts, d1_wih, d1_whh, d1_bih, d1_bhh,
                                         hcur, hnxt, cS, d2in, t);
    float* tmp = hcur; hcur = hnxt; hnxt = tmp;
  }

  // dec2 layer 0
  k_gemm<<<dim3(30,8,2),256,0,stream>>>(d2in, w2_ih0, xg, b2_ih0, b2_hh0,
                                        512, 1024, (size_t)1024*512, (size_t)3840*1024, 1024);
  k_rec<<<dim3(32,2),256,0,stream>>>(xg, w2_hh0, l0);
  // dec2 layer 1
  k_gemm<<<dim3(30,8,2),256,0,stream>>>(l0, w2_ih1, xg, b2_ih1, b2_hh1,
                                        512, 1024, (size_t)1024*512, (size_t)3840*1024, 1024);
  k_rec<<<dim3(32,2),256,0,stream>>>(xg, w2_hh1, l1);
  // output projection
  k_gemm<<<dim3(30,1,1),256,0,stream>>>(l1, out_w, (float*)d_out, out_b, nullptr,
                                        512, 128, 0, 0, 0);
}

// Round 3
// 4585.266 us; speedup vs baseline: 1.6142x; 1.6142x over previous
//
#include <hip/hip_runtime.h>

#define B_    64
#define L1C   4093
#define L2C   4086
#define L3C   4071
#define TDEC  60

static __device__ __forceinline__ float sigf(float x){ return 1.f/(1.f + __expf(-x)); }
static __device__ __forceinline__ float dot4(float4 w, float4 x){
  return fmaf(w.x,x.x, fmaf(w.y,x.y, fmaf(w.z,x.z, w.w*x.w)));
}
static __device__ __forceinline__ unsigned f2bf(float f){
  unsigned u = __float_as_uint(f);
  u = u + 0x7fffu + ((u >> 16) & 1u);   // RNE to bf16
  return (u >> 16);
}

// ---------------- conv stack ----------------
template<int CIN,int COUT,int KW,bool BF16OUT>
__global__ __launch_bounds__(256) void k_conv(
    const float* __restrict__ in, const float* __restrict__ w,
    const float* __restrict__ bias, void* __restrict__ outp,
    int Lin_, int Lout_)
{
  int g = blockIdx.x*256 + threadIdx.x;
  int bi = g / Lout_;
  int l  = g - bi*Lout_;
  if (bi >= B_) return;
  float acc[COUT];
#pragma unroll
  for (int o=0;o<COUT;o++) acc[o] = bias[o];
  const float* ip = in + ((size_t)bi*Lin_ + l)*CIN;
  for (int k=0;k<KW;k++){
#pragma unroll
    for (int i4=0;i4<CIN/4;i4++){
      float4 xv = *(const float4*)(ip + k*CIN + i4*4);
#pragma unroll
      for (int c=0;c<4;c++){
        float xs = (&xv.x)[c];
        int i = i4*4+c;
#pragma unroll
        for (int o=0;o<COUT;o++)
          acc[o] = fmaf(xs, w[(o*CIN + i)*KW + k], acc[o]);
      }
    }
  }
  if constexpr (BF16OUT){
    unsigned* op = (unsigned*)outp + ((size_t)bi*Lout_ + l)*(COUT/2);
#pragma unroll
    for (int o2=0;o2<COUT/2;o2++){
      unsigned lo = f2bf(fmaxf(acc[2*o2],0.f));
      unsigned hi = f2bf(fmaxf(acc[2*o2+1],0.f));
      op[o2] = lo | (hi<<16);
    }
  } else {
    float* op = (float*)outp + ((size_t)bi*Lout_ + l)*COUT;
#pragma unroll
    for (int o=0;o<COUT;o++) op[o] = fmaxf(acc[o],0.f);
  }
}

// ---------------- dec1: attention scan (per step) ----------------
__global__ __launch_bounds__(256) void k_attn(
    const unsigned* __restrict__ enc, const float* __restrict__ attn_w,
    const float* __restrict__ h_state, float* __restrict__ parts)
{
  int chunk = blockIdx.x, b = blockIdx.y, tid = threadIdx.x;
  int lc0 = chunk*512;
  int len = min(512, L3C - lc0);
  __shared__ __align__(16) unsigned encT[512*16];
  __shared__ float vl[2][32];
  __shared__ float e_l[2][512];
  __shared__ float red[256];
  __shared__ float scr[512];
  {
    const uint4* src = (const uint4*)(enc + ((size_t)b*L3C + lc0)*16);
    int n4 = len*4;
    for (int i = tid; i < 2048; i += 256){
      uint4 v = (i < n4) ? src[i] : make_uint4(0,0,0,0);
      ((uint4*)encT)[i] = v;
    }
  }
  {
    int c = tid & 31, d = (tid>>5)&1, part = tid>>6;
    const float* hp = h_state + (size_t)d*16384 + (size_t)b*256 + part*64;
    const float* wp = attn_w + (size_t)(part*64)*32 + c;
    float s = 0.f;
    for (int u=0;u<64;u++) s = fmaf(hp[u], wp[u*32], s);
    red[tid] = s;
  }
  __syncthreads();
  if (tid < 64){
    float v = red[tid] + red[tid+64] + red[tid+128] + red[tid+192];
    vl[tid>>5][tid&31] = v;
  }
  __syncthreads();
  for (int d=0; d<2; d++){
    float al[2];
#pragma unroll
    for (int r=0;r<2;r++){
      int l = r*256 + tid;
      const unsigned* ep = encT + l*16;
      float s = 0.f;
#pragma unroll
      for (int c2=0;c2<16;c2++){
        unsigned u = ep[c2];
        s = fmaf(__uint_as_float(u<<16),        vl[d][2*c2],   s);
        s = fmaf(__uint_as_float(u & 0xffff0000u), vl[d][2*c2+1], s);
      }
      al[r] = (l < len) ? s : -3.0e38f;
    }
    float m = fmaxf(al[0], al[1]);
#pragma unroll
    for (int off=32; off; off>>=1) m = fmaxf(m, __shfl_xor(m, off));
    if ((tid&63)==0) red[tid>>6] = m;
    __syncthreads();
    m = fmaxf(fmaxf(red[0],red[1]), fmaxf(red[2],red[3]));
    float ssum = 0.f;
#pragma unroll
    for (int r=0;r<2;r++){
      int l = r*256 + tid;
      float e = (l < len) ? __expf(al[r]-m) : 0.f;
      e_l[d][l] = e;
      ssum += e;
    }
#pragma unroll
    for (int off=32; off; off>>=1) ssum += __shfl_xor(ssum, off);
    if ((tid&63)==0) red[4 + (tid>>6)] = ssum;
    __syncthreads();
    float S = red[4]+red[5]+red[6]+red[7];
    int c2 = tid & 15, grp = tid >> 4;
    float a0=0.f, a1=0.f;
    for (int l=grp; l<512; l+=16){
      float e = e_l[d][l];
      unsigned u = encT[l*16 + c2];
      a0 = fmaf(e, __uint_as_float(u<<16),         a0);
      a1 = fmaf(e, __uint_as_float(u & 0xffff0000u), a1);
    }
    scr[(grp*16 + c2)*2 + 0] = a0;
    scr[(grp*16 + c2)*2 + 1] = a1;
    __syncthreads();
    float* pp = parts + (size_t)(((d*64 + b)*8) + chunk)*34;
    if (tid < 32){
      int cc2 = tid>>1, comp = tid&1;
      float s2 = 0.f;
#pragma unroll
      for (int gg=0; gg<16; gg++) s2 += scr[(gg*16+cc2)*2+comp];
      pp[2 + cc2*2 + comp] = s2;
    }
    if (tid==32) pp[0] = m;
    if (tid==33) pp[1] = S;
    __syncthreads();
  }
}

// ---------------- dec1: combine + LSTM cell (per step) ----------------
__global__ __launch_bounds__(256) void k_lstm1(
    const float* __restrict__ parts,
    const float* __restrict__ wih, const float* __restrict__ whh,
    const float* __restrict__ bih, const float* __restrict__ bhh,
    const float* __restrict__ h_in, float* __restrict__ h_out,
    float* __restrict__ c_state, float* __restrict__ d2in, int t)
{
  int uc = blockIdx.x, d = blockIdx.y, tid = threadIdx.x;
  __shared__ __align__(16) float ctxs[64][36];
  if (tid < 64){
    int b = tid;
    const float* pp = parts + (size_t)((d*64 + b)*8)*34;
    float M = -3.0e38f;
#pragma unroll
    for (int ch=0;ch<8;ch++) M = fmaxf(M, pp[ch*34]);
    float S = 0.f; float wx[8];
#pragma unroll
    for (int ch=0;ch<8;ch++){ wx[ch] = __expf(pp[ch*34]-M); S = fmaf(pp[ch*34+1], wx[ch], S); }
    float inv = 1.f/S;
#pragma unroll
    for (int c=0;c<32;c++){
      float s = 0.f;
#pragma unroll
      for (int ch=0;ch<8;ch++) s = fmaf(pp[ch*34+2+c], wx[ch], s);
      ctxs[b][c] = s*inv;
    }
  }
  __syncthreads();
  int ul = tid & 7, bp = tid >> 3;
  int u = uc*8 + ul;
  int b0 = bp*2;
  float g[4][2];
#pragma unroll
  for (int q=0;q<4;q++){
    float bs = bih[d*1024 + q*256 + u] + bhh[d*1024 + q*256 + u];
    g[q][0] = bs; g[q][1] = bs;
  }
#pragma unroll
  for (int c4=0;c4<8;c4++){
    float4 x0 = *(const float4*)&ctxs[b0][c4*4];
    float4 x1 = *(const float4*)&ctxs[b0+1][c4*4];
#pragma unroll
    for (int q=0;q<4;q++){
      float4 w4 = *(const float4*)(wih + (size_t)(d*1024 + q*256 + u)*32 + c4*4);
      g[q][0] += dot4(w4,x0); g[q][1] += dot4(w4,x1);
    }
  }
  const float* hb0 = h_in + (size_t)d*16384 + (size_t)b0*256;
  for (int j4=0;j4<64;j4++){
    float4 h0 = *(const float4*)(hb0 + j4*4);
    float4 h1 = *(const float4*)(hb0 + 256 + j4*4);
#pragma unroll
    for (int q=0;q<4;q++){
      float4 w4 = *(const float4*)(whh + (size_t)(d*1024 + q*256 + u)*256 + j4*4);
      g[q][0] += dot4(w4,h0); g[q][1] += dot4(w4,h1);
    }
  }
#pragma unroll
  for (int b2=0;b2<2;b2++){
    int b = b0 + b2;
    float ii = sigf(g[0][b2]);
    float ff = sigf(g[1][b2]);
    float gg = tanhf(g[2][b2]);
    float oo = sigf(g[3][b2]);
    size_t idx = (size_t)d*16384 + (size_t)b*256 + u;
    float cn = fmaf(ff, c_state[idx], ii*gg);
    float hn = oo * tanhf(cn);
    c_state[idx] = cn;
    h_out[idx] = hn;
    int tout = d ? (59 - t) : t;
    d2in[((size_t)b*60 + tout)*512 + d*256 + u] = hn;
  }
}

// ---------------- generic fp32 GEMM ----------------
__global__ __launch_bounds__(256) void k_gemm(
    const float* __restrict__ A, const float* __restrict__ W,
    float* __restrict__ C, const float* __restrict__ b1, const float* __restrict__ b2,
    int K, int ldc, size_t sW, size_t sC, int sB)
{
  int m0 = blockIdx.x * 128, n0 = blockIdx.y * 128, z = blockIdx.z;
  const float* Wz = W + (size_t)z*sW;
  float* Cz = C + (size_t)z*sC;
  const float* b1z = b1 + (size_t)z*sB;
  const float* b2z = b2 ? (b2 + (size_t)z*sB) : nullptr;
  __shared__ __align__(16) float As[16][132];
  __shared__ __align__(16) float Bs[16][132];
  int tid = threadIdx.x;
  int tx = tid & 15, ty = tid >> 4;
  int r = tid >> 2, c4 = tid & 3;
  float acc[8][8] = {};
  for (int k0=0; k0<K; k0+=16){
#pragma unroll
    for (int h=0; h<2; h++){
      int rr = r + h*64;
      float4 av = *(const float4*)(A  + (size_t)(m0+rr)*K + k0 + c4*4);
      float4 bv = *(const float4*)(Wz + (size_t)(n0+rr)*K + k0 + c4*4);
      As[c4*4+0][rr]=av.x; As[c4*4+1][rr]=av.y; As[c4*4+2][rr]=av.z; As[c4*4+3][rr]=av.w;
      Bs[c4*4+0][rr]=bv.x; Bs[c4*4+1][rr]=bv.y; Bs[c4*4+2][rr]=bv.z; Bs[c4*4+3][rr]=bv.w;
    }
    __syncthreads();
#pragma unroll
    for (int kk=0; kk<16; kk++){
      float a[8], bb[8];
      *(float4*)&a[0]  = *(const float4*)&As[kk][ty*8];
      *(float4*)&a[4]  = *(const float4*)&As[kk][ty*8+4];
      *(float4*)&bb[0] = *(const float4*)&Bs[kk][tx*8];
      *(float4*)&bb[4] = *(const float4*)&Bs[kk][tx*8+4];
#pragma unroll
      for (int i=0;i<8;i++)
#pragma unroll
        for (int j=0;j<8;j++)
          acc[i][j] = fmaf(a[i], bb[j], acc[i][j]);
    }
    __syncthreads();
  }
  float bb1[8];
#pragma unroll
  for (int j=0;j<8;j++){
    int n = n0 + tx*8 + j;
    bb1[j] = b1z[n] + (b2z ? b2z[n] : 0.f);
  }
#pragma unroll
  for (int i=0;i<8;i++){
    int m = m0 + ty*8 + i;
    float o[8];
#pragma unroll
    for (int j=0;j<8;j++) o[j] = acc[i][j] + bb1[j];
    *(float4*)(Cz + (size_t)m*ldc + n0 + tx*8)     = *(const float4*)&o[0];
    *(float4*)(Cz + (size_t)m*ldc + n0 + tx*8 + 4) = *(const float4*)&o[4];
  }
}

// ---------------- dec2: pack whh -> transposed bf16x8 [d][j8][row] ----------------
__global__ __launch_bounds__(256) void k_packw(
    const float* __restrict__ whh, uint4* __restrict__ wT)
{
  int gid = blockIdx.x*256 + threadIdx.x;   // 2*32*1024 = 65536
  int d = gid >> 15, j8 = (gid>>10)&31, row = gid & 1023;
  const float* src = whh + ((size_t)d*1024 + row)*256 + j8*8;
  float4 a = *(const float4*)src;
  float4 b = *(const float4*)(src+4);
  uint4 o;
  o.x = f2bf(a.x) | (f2bf(a.y)<<16);
  o.y = f2bf(a.z) | (f2bf(a.w)<<16);
  o.z = f2bf(b.x) | (f2bf(b.y)<<16);
  o.w = f2bf(b.z) | (f2bf(b.w)<<16);
  wT[gid] = o;
}

// ---------------- dec2: recurrent, block = (dir, batch), 16 waves ----------------
// h in LDS (broadcast), gate exchange via LDS, weights bf16 transposed (coalesced).
__global__ __launch_bounds__(1024) void k_rec2(
    const float* __restrict__ xg,   // [2][64][60][1024] = x@wih^T + biases
    const uint4* __restrict__ wT,   // [2][32][1024] bf16x8 packed
    float* __restrict__ out)        // [64][60][512]
{
  int b = blockIdx.x, d = blockIdx.y, tid = threadIdx.x;
  __shared__ __align__(16) float hls[256];
  __shared__ float gls[1024];
  float c = 0.f;
  if (tid < 256) hls[tid] = 0.f;
  __syncthreads();
  const uint4* wp = wT + (size_t)d*32*1024;
  const float* xp = xg + (((size_t)d*64 + b)*60)*1024;
  for (int step=0; step<TDEC; step++){
    int t = d ? (TDEC-1-step) : step;
    float g = xp[(size_t)t*1024 + tid];
#pragma unroll 4
    for (int j8=0;j8<32;j8++){
      uint4 wv = wp[j8*1024 + tid];
      float4 h0 = *(const float4*)&hls[j8*8];
      float4 h1 = *(const float4*)&hls[j8*8+4];
      g = fmaf(__uint_as_float(wv.x<<16),          h0.x, g);
      g = fmaf(__uint_as_float(wv.x&0xffff0000u),  h0.y, g);
      g = fmaf(__uint_as_float(wv.y<<16),          h0.z, g);
      g = fmaf(__uint_as_float(wv.y&0xffff0000u),  h0.w, g);
      g = fmaf(__uint_as_float(wv.z<<16),          h1.x, g);
      g = fmaf(__uint_as_float(wv.z&0xffff0000u),  h1.y, g);
      g = fmaf(__uint_as_float(wv.w<<16),          h1.z, g);
      g = fmaf(__uint_as_float(wv.w&0xffff0000u),  h1.w, g);
    }
    gls[tid] = g;
    __syncthreads();
    if (tid < 256){
      float ii = sigf(gls[tid]);
      float ff = sigf(gls[256+tid]);
      float gg = tanhf(gls[512+tid]);
      float oo = sigf(gls[768+tid]);
      c = fmaf(ff, c, ii*gg);
      float hn = oo * tanhf(c);
      hls[tid] = hn;
      out[((size_t)b*60 + t)*512 + d*256 + tid] = hn;
    }
    __syncthreads();
  }
}

extern "C" void kernel_launch(void* const* d_in, const int* in_sizes, int n_in,
                              void* d_out, int out_size, void* d_ws, size_t ws_size,
                              hipStream_t stream) {
  const float* x      = (const float*)d_in[0];
  const float* cw1    = (const float*)d_in[1];
  const float* cb1    = (const float*)d_in[2];
  const float* cw2    = (const float*)d_in[3];
  const float* cb2    = (const float*)d_in[4];
  const float* cw3    = (const float*)d_in[5];
  const float* cb3    = (const float*)d_in[6];
  const float* attn_w = (const float*)d_in[7];
  // d_in[8] attn_b: constant over softmax axis -> drops out analytically
  const float* d1_wih = (const float*)d_in[9];
  const float* d1_whh = (const float*)d_in[10];
  const float* d1_bih = (const float*)d_in[11];
  const float* d1_bhh = (const float*)d_in[12];
  const float* w2_ih0 = (const float*)d_in[13];
  const float* w2_hh0 = (const float*)d_in[14];
  const float* b2_ih0 = (const float*)d_in[15];
  const float* b2_hh0 = (const float*)d_in[16];
  const float* w2_ih1 = (const float*)d_in[17];
  const float* w2_hh1 = (const float*)d_in[18];
  const float* b2_ih1 = (const float*)d_in[19];
  const float* b2_hh1 = (const float*)d_in[20];
  const float* out_w  = (const float*)d_in[21];
  const float* out_b  = (const float*)d_in[22];

  char* ws = (char*)d_ws;
  size_t off = 0;
  // enc bf16-packed (B, L3C, 32ch) = 16,674,816 B; pad to 16,675,840.
  unsigned* enc = (unsigned*)(ws + off); off += 16675840;
  size_t off_h1 = off;
  float* h1buf = (float*)(ws + off); off += 8382464;               // (B,4093,8)
  float* h2buf = (float*)(ws + off); off += 16736256;              // (B,4086,16)
  float* d2in  = (float*)(ws + off_h1);                            // reuse: (B,60,512) 7.86MB
  float* l0    = (float*)(ws + off_h1 + 7864320);
  float* l1    = (float*)(ws + off_h1 + 15728640);
  // wT: 1MB, in the dead tail of the h1/h2 region (l1 ends at off_h1+23,592,960;
  // region extends to off_h1+25,118,720). Packed fresh before each k_rec2.
  uint4* wT    = (uint4*)(ws + off_h1 + 23592960);
  float* xg    = (float*)(ws + off); off += 31457280;              // [2][B][60][1024]
  float* hA    = (float*)(ws + off); off += 131072;                // h dbuf A [2][B][256]
  float* hB    = (float*)(ws + off); off += 131072;                // h dbuf B
  float* cS    = (float*)(ws + off); off += 131072;                // c state
  float* parts = (float*)(ws + off); off += 2*64*8*34*4;           // attn partials
  (void)ws_size; (void)in_sizes; (void)n_in; (void)out_size;

  hipMemsetAsync(hA, 0, 3*131072, stream);   // zero hA, hB, cS (contiguous)

  int g1 = (B_*L1C + 255)/256;
  k_conv<64,8,4,false><<<g1,256,0,stream>>>(x, cw1, cb1, h1buf, 4096, L1C);
  int g2 = (B_*L2C + 255)/256;
  k_conv<8,16,8,false><<<g2,256,0,stream>>>(h1buf, cw2, cb2, h2buf, L1C, L2C);
  int g3 = (B_*L3C + 255)/256;
  k_conv<16,32,16,true><<<g3,256,0,stream>>>(h2buf, cw3, cb3, enc, L2C, L3C);

  float* hcur = hA; float* hnxt = hB;
  for (int t=0; t<TDEC; t++){
    k_attn<<<dim3(8,64),256,0,stream>>>(enc, attn_w, hcur, parts);
    k_lstm1<<<dim3(32,2),256,0,stream>>>(parts, d1_wih, d1_whh, d1_bih, d1_bhh,
                                         hcur, hnxt, cS, d2in, t);
    float* tmp = hcur; hcur = hnxt; hnxt = tmp;
  }

  // dec2 layer 0
  k_packw<<<256,256,0,stream>>>(w2_hh0, wT);
  k_gemm<<<dim3(30,8,2),256,0,stream>>>(d2in, w2_ih0, xg, b2_ih0, b2_hh0,
                                        512, 1024, (size_t)1024*512, (size_t)3840*1024, 1024);
  k_rec2<<<dim3(64,2),1024,0,stream>>>(xg, wT, l0);
  // dec2 layer 1
  k_packw<<<256,256,0,stream>>>(w2_hh1, wT);
  k_gemm<<<dim3(30,8,2),256,0,stream>>>(l0, w2_ih1, xg, b2_ih1, b2_hh1,
                                        512, 1024, (size_t)1024*512, (size_t)3840*1024, 1024);
  k_rec2<<<dim3(64,2),1024,0,stream>>>(xg, wT, l1);
  // output projection
  k_gemm<<<dim3(30,1,1),256,0,stream>>>(l1, out_w, (float*)d_out, out_b, nullptr,
                                        512, 128, 0, 0, 0);
}